// Round 10
// baseline (136.966 us; speedup 1.0000x reference)
//
#include <hip/hip_runtime.h>
#include <stdint.h>

// ---------------------------------------------------------------------------
// CritiGraph distance kernel: bit-exact reproduction of the JAX reference
// (jax_threefry_partitionable=True path, verified absmax 0.0).
//
// Round-9 DECOMPOSITION ROUND (resubmitted after timeout). Real kernel
// identical to round-8 (117.85us single-launch). A second "probe" kernel
// runs after it: identical compute + LDS scatter, same grid/block/LDS/
// occupancy, but NO staging reads / NO global stores (LDS kept live via asm
// sink). With R3's identity OH + K_dist = 117.85,
//   K_probe = dur - 117.85          (stream gap cancels)
//   store_cost = K_dist - K_probe = 21.1 - K_probe.
// Decision: K_probe >= 18.5us -> compute-bound, attack VALU count;
//           K_probe <= 16us   -> stores serialized, attack overlap/NT.
// ---------------------------------------------------------------------------

#define H_   16
#define TP_  16
#define K_   16
#define T_   2048
#define NC   513                       // 2*H*K + 1
#define ROWS 4
#define GRID (T_ / ROWS)               // 512 blocks, 2 per CU

typedef float f32x4 __attribute__((ext_vector_type(4)));

struct TFPair { uint32_t a, b; };

__host__ __device__ constexpr uint32_t rotl32(uint32_t x, int r) {
  return (x << r) | (x >> (32 - r));
}

__host__ __device__ constexpr TFPair tf2x32(uint32_t k0, uint32_t k1,
                                            uint32_t x0, uint32_t x1) {
  uint32_t ks0 = k0, ks1 = k1, ks2 = k0 ^ k1 ^ 0x1BD11BDAu;
  x0 += ks0; x1 += ks1;
  x0 += x1; x1 = rotl32(x1, 13); x1 ^= x0;
  x0 += x1; x1 = rotl32(x1, 15); x1 ^= x0;
  x0 += x1; x1 = rotl32(x1, 26); x1 ^= x0;
  x0 += x1; x1 = rotl32(x1,  6); x1 ^= x0;
  x0 += ks1; x1 += ks2 + 1u;
  x0 += x1; x1 = rotl32(x1, 17); x1 ^= x0;
  x0 += x1; x1 = rotl32(x1, 29); x1 ^= x0;
  x0 += x1; x1 = rotl32(x1, 16); x1 ^= x0;
  x0 += x1; x1 = rotl32(x1, 24); x1 ^= x0;
  x0 += ks2; x1 += ks0 + 2u;
  x0 += x1; x1 = rotl32(x1, 13); x1 ^= x0;
  x0 += x1; x1 = rotl32(x1, 15); x1 ^= x0;
  x0 += x1; x1 = rotl32(x1, 26); x1 ^= x0;
  x0 += x1; x1 = rotl32(x1,  6); x1 ^= x0;
  x0 += ks0; x1 += ks1 + 3u;
  x0 += x1; x1 = rotl32(x1, 17); x1 ^= x0;
  x0 += x1; x1 = rotl32(x1, 29); x1 ^= x0;
  x0 += x1; x1 = rotl32(x1, 16); x1 ^= x0;
  x0 += x1; x1 = rotl32(x1, 24); x1 ^= x0;
  x0 += ks1; x1 += ks2 + 4u;
  x0 += x1; x1 = rotl32(x1, 13); x1 ^= x0;
  x0 += x1; x1 = rotl32(x1, 15); x1 ^= x0;
  x0 += x1; x1 = rotl32(x1, 26); x1 ^= x0;
  x0 += x1; x1 = rotl32(x1,  6); x1 ^= x0;
  x0 += ks2; x1 += ks0 + 5u;
  return {x0, x1};
}

// ---- compile-time key derivation (jax.random.key(42) == (0,42)) -----------
constexpr TFPair KM = tf2x32(0u, 42u, 0u, 0u);   // kmask = split(key)[0]
constexpr TFPair KP = tf2x32(0u, 42u, 0u, 1u);   // kperm = split(key)[1]
constexpr TFPair C2 = tf2x32(KM.a, KM.b, 0u, 1u);   // k2 of split(kmask)
constexpr uint32_t KLO0 = C2.a, KLO1 = C2.b;
constexpr TFPair SB = tf2x32(KP.a, KP.b, 0u, 1u);   // subkey of split(kperm)
constexpr uint32_t KSUB0 = SB.a, KSUB1 = SB.b;

// ---- compile-time permutation: inv_perm[m] = stable rank of sortkey[m] ----
struct Keys { uint32_t v[NC]; };
constexpr Keys make_keys() {
  Keys k{};
  for (int i = 0; i < NC; ++i) {
    TFPair r = tf2x32(KSUB0, KSUB1, 0u, (uint32_t)i);
    k.v[i] = r.a ^ r.b;          // 32-bit random_bits, partitionable: hi^lo
  }
  return k;
}
constexpr Keys KEYS = make_keys();

#define PART_SZ 33
struct Part { int v[PART_SZ]; };
constexpr Part make_part(int lo) {
  Part p{};
  for (int m = lo; m < lo + PART_SZ && m < NC; ++m) {
    uint32_t km = KEYS.v[m];
    int rank = 0;
    for (int j = 0; j < NC; ++j) {
      uint32_t kj = KEYS.v[j];
      if (kj < km || (kj == km && j < m)) ++rank;
    }
    p.v[m - lo] = rank;
  }
  return p;
}
// 16 separate constexpr variables: each gets its own constexpr step budget.
constexpr Part PT0  = make_part(0),   PT1  = make_part(33),
               PT2  = make_part(66),  PT3  = make_part(99),
               PT4  = make_part(132), PT5  = make_part(165),
               PT6  = make_part(198), PT7  = make_part(231),
               PT8  = make_part(264), PT9  = make_part(297),
               PT10 = make_part(330), PT11 = make_part(363),
               PT12 = make_part(396), PT13 = make_part(429),
               PT14 = make_part(462), PT15 = make_part(495);

struct IPerm { int v[NC]; };
constexpr IPerm merge_parts() {
  IPerm r{};
  const Part* ps[16] = {&PT0, &PT1, &PT2,  &PT3,  &PT4,  &PT5,  &PT6,  &PT7,
                        &PT8, &PT9, &PT10, &PT11, &PT12, &PT13, &PT14, &PT15};
  for (int c = 0; c < 16; ++c)
    for (int i = 0; i < PART_SZ; ++i) {
      int m = c * PART_SZ + i;
      if (m < NC) r.v[m] = ps[c]->v[i];
    }
  return r;
}
constexpr IPerm IPERM = merge_parts();
constexpr int C_ORI = IPERM.v[256];     // output channel of the 'ori' column

// Packed channel-pair table: low16 = channel of +result (j), high16 = channel
// of -result (j+257).  Indexed by j = jl*16 + jj.
struct CTab { uint32_t v[256]; };
constexpr CTab make_ctab() {
  CTab c{};
  for (int j = 0; j < 256; ++j)
    c.v[j] = (uint32_t)IPERM.v[j] | ((uint32_t)IPERM.v[j + 257] << 16);
  return c;
}
constexpr CTab CTAB = make_ctab();
__device__ __constant__ CTab d_ctab = CTAB;

__device__ __forceinline__ void sbar_lgkm() {
  __builtin_amdgcn_sched_barrier(0);
  asm volatile("s_waitcnt lgkmcnt(0)" ::: "memory");
  __builtin_amdgcn_s_barrier();
  __builtin_amdgcn_sched_barrier(0);
}

// Compute one t-row into the LDS buffer. If DO_ST, interleave the previous
// row's 8 NT stores (from the stg registers) one per 2 jj iterations.
template <bool DO_ST>
__device__ __forceinline__ void compute_row(
    int ori, float nm, uint32_t base, uint32_t flip_h, uint32_t mask_h,
    const uint32_t* __restrict__ ct, float* __restrict__ buf,
    int tid, int tp, const f32x4* __restrict__ stg, f32x4* __restrict__ o4p) {
  const float nm16 = nm * 0.0625f;
  const uint32_t ao = (uint32_t)(ori < 0 ? -ori : ori);

  // the 'ori' channel: dist(ori,ori) = (1 - 1/16)*norm
  if (tid < 16) buf[C_ORI * TP_ + tid] = 0.9375f * nm;

#pragma unroll
  for (int jj = 0; jj < 16; ++jj) {
    // flat index into (H, T, K, TP) mask tensor; k == jj
    const TFPair r = tf2x32(KLO0, KLO1, 0u, base + (uint32_t)(jj * TP_));
    // flip bit h, xor the (2^h-1)-masked random bits
    const uint32_t fm = flip_h ^ (r.b & mask_h);
    const int v = ori ^ (int)fm;

    // dist(v,ori) = sign(v)*sign(ori) * (1 - bitlen(|v|^|ori|+1)/16) * norm
    const uint32_t sgbit = ((uint32_t)(v ^ ori)) & 0x80000000u;
    const uint32_t av = (uint32_t)(v < 0 ? -v : v);
    const uint32_t x  = (av ^ ao) + 1u;                // <= 2^16, exact f32
    const int e = 32 - __clz((int)x);                  // bit length
    const float f  = nm - (float)e * nm16;             // (1 - e/16)*nm
    const float d1 = __uint_as_float(__float_as_uint(f) ^ sgbit);
    // dist(-v, ori): |v| unchanged, sign flips unless v==0
    const float d2 = (v == 0) ? d1
                   : __uint_as_float(__float_as_uint(d1) ^ 0x80000000u);

    const uint32_t pr = ct[jj];
    buf[(pr & 0xffffu) * TP_ + tp] = d1;
    buf[(pr >> 16)     * TP_ + tp] = d2;

    if (DO_ST && (jj & 1)) {
      const int s = jj >> 1;                           // compile-time (unrolled)
      __builtin_nontemporal_store(stg[s], o4p + (s << 8) + tid);
      __builtin_amdgcn_sched_barrier(0);               // keep issue spread
    }
  }
}

// ---- dist kernel: 512 blocks x 4 rows, 256 thr = 16tp x 16jl --------------
__global__ __launch_bounds__(256, 2) void dist_kernel(
    const int* __restrict__ locations, const int* __restrict__ pos_idx,
    const float* __restrict__ norm, float* __restrict__ out) {
  __shared__ __align__(16) float buf[NC * TP_];   // 513*16 floats = 32832 B

  const int tid = (int)threadIdx.x;
  const int tp  = tid & 15;
  const int jl  = tid >> 4;                 // == h for this thread's 16 j's
  const int t0  = (int)blockIdx.x * ROWS;

  // per-thread packed channel pairs (statically indexed -> registers)
  uint32_t ct[16];
#pragma unroll
  for (int i = 0; i < 16; ++i) ct[i] = d_ctab.v[(jl << 4) + i];

  const uint32_t flip_h = 1u << jl;
  const uint32_t mask_h = flip_h - 1u;
  const f32x4* __restrict__ b4 = (const f32x4*)buf;

  f32x4 stg[8];                             // staged previous row (32 VGPR)

  // gathers: current row + rotation prefetch of the next
  int   ori_c = locations[pos_idx[t0] * TP_ + tp];
  float nm_c  = norm[t0];
  int   ori_n = locations[pos_idx[t0 + 1] * TP_ + tp];
  float nm_n  = norm[t0 + 1];

  // ---- peel row 0: compute only (nothing staged yet) ----------------------
  {
    const uint32_t base = (uint32_t)(((jl * T_ + t0) * K_) * TP_ + tp);
    compute_row<false>(ori_c, nm_c, base, flip_h, mask_h, ct, buf, tid, tp,
                       nullptr, nullptr);
    sbar_lgkm();                            // scatter visible
#pragma unroll
    for (int s = 0; s < 8; ++s) stg[s] = b4[(s << 8) + tid];
    if (tid < 4) {                          // tail: elements 2048..2051
      f32x4 tl = b4[2048 + tid];
      __builtin_nontemporal_store(
          tl, (f32x4*)(out + (size_t)t0 * (NC * TP_)) + 2048 + tid);
    }
    sbar_lgkm();                            // reads done -> buffer reusable
    ori_c = ori_n; nm_c = nm_n;
  }

  // ---- rows 1..ROWS-1: compute row r, interleave stores of row r-1 --------
#pragma unroll 1
  for (int row = 1; row < ROWS; ++row) {
    const int t = t0 + row;
    if (row + 1 < ROWS) {                   // prefetch next row's gather
      ori_n = locations[pos_idx[t + 1] * TP_ + tp];
      nm_n  = norm[t + 1];
    }

    f32x4* __restrict__ o4_prev = (f32x4*)(out + (size_t)(t - 1) * (NC * TP_));
    const uint32_t base = (uint32_t)(((jl * T_ + t) * K_) * TP_ + tp);
    compute_row<true>(ori_c, nm_c, base, flip_h, mask_h, ct, buf, tid, tp,
                      stg, o4_prev);

    sbar_lgkm();                            // scatter of row r visible
#pragma unroll
    for (int s = 0; s < 8; ++s) stg[s] = b4[(s << 8) + tid];
    if (tid < 4) {                          // tail of row r
      f32x4 tl = b4[2048 + tid];
      __builtin_nontemporal_store(
          tl, (f32x4*)(out + (size_t)t * (NC * TP_)) + 2048 + tid);
    }
    sbar_lgkm();                            // reads done -> buffer reusable
    ori_c = ori_n; nm_c = nm_n;
  }

  // ---- final burst: last row's main stores --------------------------------
  {
    f32x4* __restrict__ o4 =
        (f32x4*)(out + (size_t)(t0 + ROWS - 1) * (NC * TP_));
#pragma unroll
    for (int s = 0; s < 8; ++s)
      __builtin_nontemporal_store(stg[s], o4 + (s << 8) + tid);
  }
}

// ---- probe kernel: identical compute + LDS scatter, NO global stores ------
// Same grid/block/LDS/launch_bounds as dist_kernel so occupancy matches.
// LDS writes kept live via an asm sink read; out is untouched.
__global__ __launch_bounds__(256, 2) void probe_kernel(
    const int* __restrict__ locations, const int* __restrict__ pos_idx,
    const float* __restrict__ norm) {
  __shared__ __align__(16) float buf[NC * TP_];

  const int tid = (int)threadIdx.x;
  const int tp  = tid & 15;
  const int jl  = tid >> 4;
  const int t0  = (int)blockIdx.x * ROWS;

  uint32_t ct[16];
#pragma unroll
  for (int i = 0; i < 16; ++i) ct[i] = d_ctab.v[(jl << 4) + i];

  const uint32_t flip_h = 1u << jl;
  const uint32_t mask_h = flip_h - 1u;

  int   ori_c = locations[pos_idx[t0] * TP_ + tp];
  float nm_c  = norm[t0];

#pragma unroll 1
  for (int row = 0; row < ROWS; ++row) {
    const int t = t0 + row;
    int ori_n = 0; float nm_n = 0.0f;
    if (row + 1 < ROWS) {
      ori_n = locations[pos_idx[t + 1] * TP_ + tp];
      nm_n  = norm[t + 1];
    }
    const uint32_t base = (uint32_t)(((jl * T_ + t) * K_) * TP_ + tp);
    compute_row<false>(ori_c, nm_c, base, flip_h, mask_h, ct, buf, tid, tp,
                       nullptr, nullptr);
    sbar_lgkm();                            // same barrier cost as real kernel
    ori_c = ori_n; nm_c = nm_n;
  }
  // keep the LDS results (and thus all compute) observable
  float sink = buf[tid];
  asm volatile("" :: "v"(sink) : "memory");
}

extern "C" void kernel_launch(void* const* d_in, const int* in_sizes, int n_in,
                              void* d_out, int out_size, void* d_ws, size_t ws_size,
                              hipStream_t stream) {
  const int*   locations = (const int*)d_in[0];
  const int*   pos_idx   = (const int*)d_in[1];
  const float* norm      = (const float*)d_in[2];
  float* out = (float*)d_out;

  hipLaunchKernelGGL(dist_kernel, dim3(GRID), dim3(256), 0, stream,
                     locations, pos_idx, norm, out);
  // probe: compute-only replica (writes nothing to out)
  hipLaunchKernelGGL(probe_kernel, dim3(GRID), dim3(256), 0, stream,
                     locations, pos_idx, norm);
}

// Round 11
// 117.262 us; speedup vs baseline: 1.1680x; 1.1680x over previous
//
#include <hip/hip_runtime.h>
#include <stdint.h>

// ---------------------------------------------------------------------------
// CritiGraph distance kernel: bit-exact reproduction of the JAX reference
// (jax_threefry_partitionable=True path, verified absmax 0.0).
//
// Round-11 structure (canonical-LDS + trimmed integer path):
//   R10 decomposition: store cost = K_dist - K_probe ~= 1.1 us -> stores are
//   FREE; kernel is compute-bound (~19 us vs ~15 us issue floor at the
//   ~1.55 GHz sustained VALU clock implied by m07). Lever: VALU count.
//   - sgbit eliminated: fm < 2^16 always (jl<=15) -> v,ori same sign ->
//     sg=+1 for d1. Integer-only change; verified float path untouched.
//   - CANONICAL LDS layout: d1 -> channel j, d2 -> channel j+257 (natural
//     order). Both ds_writes use one base reg + compile-time byte offset
//     (jj*64 / (jj+257)*64) -> zero per-jj address VALU (was ~6 ops).
//   - Permutation moved to the staging reads: out channel c reads LDS
//     channel P[c] (P = IPERM^-1, compile-time). 8+1 read addresses
//     precomputed once per thread (row-invariant) from a __constant__ table.
//   - Store issue stays interleaved with next row's compute (R8 scheme,
//     proven equal-or-better); probe kernel removed.
// ---------------------------------------------------------------------------

#define H_   16
#define TP_  16
#define K_   16
#define T_   2048
#define NC   513                       // 2*H*K + 1
#define ROWS 4
#define GRID (T_ / ROWS)               // 512 blocks, 2 per CU

typedef float f32x4 __attribute__((ext_vector_type(4)));

struct TFPair { uint32_t a, b; };

__host__ __device__ constexpr uint32_t rotl32(uint32_t x, int r) {
  return (x << r) | (x >> (32 - r));
}

__host__ __device__ constexpr TFPair tf2x32(uint32_t k0, uint32_t k1,
                                            uint32_t x0, uint32_t x1) {
  uint32_t ks0 = k0, ks1 = k1, ks2 = k0 ^ k1 ^ 0x1BD11BDAu;
  x0 += ks0; x1 += ks1;
  x0 += x1; x1 = rotl32(x1, 13); x1 ^= x0;
  x0 += x1; x1 = rotl32(x1, 15); x1 ^= x0;
  x0 += x1; x1 = rotl32(x1, 26); x1 ^= x0;
  x0 += x1; x1 = rotl32(x1,  6); x1 ^= x0;
  x0 += ks1; x1 += ks2 + 1u;
  x0 += x1; x1 = rotl32(x1, 17); x1 ^= x0;
  x0 += x1; x1 = rotl32(x1, 29); x1 ^= x0;
  x0 += x1; x1 = rotl32(x1, 16); x1 ^= x0;
  x0 += x1; x1 = rotl32(x1, 24); x1 ^= x0;
  x0 += ks2; x1 += ks0 + 2u;
  x0 += x1; x1 = rotl32(x1, 13); x1 ^= x0;
  x0 += x1; x1 = rotl32(x1, 15); x1 ^= x0;
  x0 += x1; x1 = rotl32(x1, 26); x1 ^= x0;
  x0 += x1; x1 = rotl32(x1,  6); x1 ^= x0;
  x0 += ks0; x1 += ks1 + 3u;
  x0 += x1; x1 = rotl32(x1, 17); x1 ^= x0;
  x0 += x1; x1 = rotl32(x1, 29); x1 ^= x0;
  x0 += x1; x1 = rotl32(x1, 16); x1 ^= x0;
  x0 += x1; x1 = rotl32(x1, 24); x1 ^= x0;
  x0 += ks1; x1 += ks2 + 4u;
  x0 += x1; x1 = rotl32(x1, 13); x1 ^= x0;
  x0 += x1; x1 = rotl32(x1, 15); x1 ^= x0;
  x0 += x1; x1 = rotl32(x1, 26); x1 ^= x0;
  x0 += x1; x1 = rotl32(x1,  6); x1 ^= x0;
  x0 += ks2; x1 += ks0 + 5u;
  return {x0, x1};
}

// ---- compile-time key derivation (jax.random.key(42) == (0,42)) -----------
constexpr TFPair KM = tf2x32(0u, 42u, 0u, 0u);   // kmask = split(key)[0]
constexpr TFPair KP = tf2x32(0u, 42u, 0u, 1u);   // kperm = split(key)[1]
constexpr TFPair C2 = tf2x32(KM.a, KM.b, 0u, 1u);   // k2 of split(kmask)
constexpr uint32_t KLO0 = C2.a, KLO1 = C2.b;
constexpr TFPair SB = tf2x32(KP.a, KP.b, 0u, 1u);   // subkey of split(kperm)
constexpr uint32_t KSUB0 = SB.a, KSUB1 = SB.b;

// ---- compile-time permutation: inv_perm[m] = stable rank of sortkey[m] ----
struct Keys { uint32_t v[NC]; };
constexpr Keys make_keys() {
  Keys k{};
  for (int i = 0; i < NC; ++i) {
    TFPair r = tf2x32(KSUB0, KSUB1, 0u, (uint32_t)i);
    k.v[i] = r.a ^ r.b;          // 32-bit random_bits, partitionable: hi^lo
  }
  return k;
}
constexpr Keys KEYS = make_keys();

#define PART_SZ 33
struct Part { int v[PART_SZ]; };
constexpr Part make_part(int lo) {
  Part p{};
  for (int m = lo; m < lo + PART_SZ && m < NC; ++m) {
    uint32_t km = KEYS.v[m];
    int rank = 0;
    for (int j = 0; j < NC; ++j) {
      uint32_t kj = KEYS.v[j];
      if (kj < km || (kj == km && j < m)) ++rank;
    }
    p.v[m - lo] = rank;
  }
  return p;
}
// 16 separate constexpr variables: each gets its own constexpr step budget.
constexpr Part PT0  = make_part(0),   PT1  = make_part(33),
               PT2  = make_part(66),  PT3  = make_part(99),
               PT4  = make_part(132), PT5  = make_part(165),
               PT6  = make_part(198), PT7  = make_part(231),
               PT8  = make_part(264), PT9  = make_part(297),
               PT10 = make_part(330), PT11 = make_part(363),
               PT12 = make_part(396), PT13 = make_part(429),
               PT14 = make_part(462), PT15 = make_part(495);

struct IPerm { int v[NC]; };
constexpr IPerm merge_parts() {
  IPerm r{};
  const Part* ps[16] = {&PT0, &PT1, &PT2,  &PT3,  &PT4,  &PT5,  &PT6,  &PT7,
                        &PT8, &PT9, &PT10, &PT11, &PT12, &PT13, &PT14, &PT15};
  for (int c = 0; c < 16; ++c)
    for (int i = 0; i < PART_SZ; ++i) {
      int m = c * PART_SZ + i;
      if (m < NC) r.v[m] = ps[c]->v[i];
    }
  return r;
}
constexpr IPerm IPERM = merge_parts();

// Forward read-address table: out channel c sources LDS (canonical) channel
// P[c] where IPERM[P[c]] = c. Stored as byte offset P[c]*64.
struct FTab { uint32_t v[NC]; };
constexpr FTab make_ftab() {
  FTab f{};
  for (int m = 0; m < NC; ++m) f.v[IPERM.v[m]] = (uint32_t)m * 64u;
  return f;
}
constexpr FTab FTAB = make_ftab();
__device__ __constant__ FTab d_ftab = FTAB;

__device__ __forceinline__ void sbar_lgkm() {
  __builtin_amdgcn_sched_barrier(0);
  asm volatile("s_waitcnt lgkmcnt(0)" ::: "memory");
  __builtin_amdgcn_s_barrier();
  __builtin_amdgcn_sched_barrier(0);
}

// Compute one t-row into the CANONICAL LDS buffer. bufp1 = buf + jl*256 + tp
// (channel j=jl*16+jj lives at bufp1[jj*16]; channel j+257 at
// bufp1[(jj+257)*16] -> both ds_write offsets are compile-time immediates).
// If DO_ST, interleave the previous row's 8 NT stores one per 2 jj.
template <bool DO_ST>
__device__ __forceinline__ void compute_row(
    int ori, float nm, uint32_t base, uint32_t flip_h, uint32_t mask_h,
    float* __restrict__ buf, float* __restrict__ bufp1,
    int tid, const f32x4* __restrict__ stg, f32x4* __restrict__ o4p) {
  const float nm16 = nm * 0.0625f;
  const uint32_t ao = (uint32_t)(ori < 0 ? -ori : ori);

  // the 'ori' channel (source index 256, canonical): dist(ori,ori)
  if (tid < 16) buf[256 * TP_ + tid] = 0.9375f * nm;

#pragma unroll
  for (int jj = 0; jj < 16; ++jj) {
    // flat index into (H, T, K, TP) mask tensor; k == jj
    const TFPair r = tf2x32(KLO0, KLO1, 0u, base + (uint32_t)(jj * TP_));
    // flip bit h, xor the (2^h-1)-masked random bits
    const uint32_t fm = flip_h ^ (r.b & mask_h);
    const int v = ori ^ (int)fm;

    // sg = sign(v)*sign(ori) = +1 ALWAYS: fm < 2^16 (jl<=15) so v and ori
    // share the sign bit. d1 = (1 - bitlen(|v|^|ori|+1)/16) * norm directly.
    const uint32_t av = (uint32_t)(v < 0 ? -v : v);
    const uint32_t x  = (av ^ ao) + 1u;                // <= 2^16, exact f32
    const int e = 32 - __clz((int)x);                  // bit length
    const float d1 = nm - (float)e * nm16;             // (1 - e/16)*nm
    // dist(-v, ori): |v| unchanged, sign flips unless v==0
    const float d2 = (v == 0) ? d1
                   : __uint_as_float(__float_as_uint(d1) ^ 0x80000000u);

    bufp1[jj * TP_]         = d1;                      // channel j
    bufp1[(jj + 257) * TP_] = d2;                      // channel j+257

    if (DO_ST && (jj & 1)) {
      const int s = jj >> 1;                           // compile-time (unrolled)
      __builtin_nontemporal_store(stg[s], o4p + (s << 8) + tid);
      __builtin_amdgcn_sched_barrier(0);               // keep issue spread
    }
  }
}

// ---- dist kernel: 512 blocks x 4 rows, 256 thr = 16tp x 16jl --------------
__global__ __launch_bounds__(256, 2) void dist_kernel(
    const int* __restrict__ locations, const int* __restrict__ pos_idx,
    const float* __restrict__ norm, float* __restrict__ out) {
  __shared__ __align__(16) float buf[NC * TP_];   // 513*16 floats = 32832 B

  const int tid = (int)threadIdx.x;
  const int tp  = tid & 15;
  const int jl  = tid >> 4;                 // == h for this thread's 16 j's
  const int t0  = (int)blockIdx.x * ROWS;

  const uint32_t flip_h = 1u << jl;
  const uint32_t mask_h = flip_h - 1u;
  float* bufp1 = buf + jl * 256 + tp;       // canonical scatter base
  const char* bufc = (const char*)buf;

  // precompute the 8 (+1 tail) permuted staging-read byte addresses
  // (row-invariant; one-time __constant__ gathers amortized over 4 rows)
  uint32_t raddr[8];
#pragma unroll
  for (int s = 0; s < 8; ++s) {
    const int o = (s << 8) + tid;           // out float4 index
    raddr[s] = d_ftab.v[o >> 2] + (uint32_t)((o & 3) << 4);
  }
  uint32_t taddr = 0;
  if (tid < 4) taddr = d_ftab.v[512] + (uint32_t)(tid << 4);

  f32x4 stg[8];                             // staged previous row (32 VGPR)

  // gathers: current row + rotation prefetch of the next
  int   ori_c = locations[pos_idx[t0] * TP_ + tp];
  float nm_c  = norm[t0];
  int   ori_n = locations[pos_idx[t0 + 1] * TP_ + tp];
  float nm_n  = norm[t0 + 1];

  // ---- peel row 0: compute only (nothing staged yet) ----------------------
  {
    const uint32_t base = (uint32_t)(((jl * T_ + t0) * K_) * TP_ + tp);
    compute_row<false>(ori_c, nm_c, base, flip_h, mask_h, buf, bufp1, tid,
                       nullptr, nullptr);
    sbar_lgkm();                            // scatter visible
#pragma unroll
    for (int s = 0; s < 8; ++s)
      stg[s] = *(const f32x4*)(bufc + raddr[s]);
    if (tid < 4) {                          // tail: out f4 2048..2051 (c=512)
      f32x4 tl = *(const f32x4*)(bufc + taddr);
      __builtin_nontemporal_store(
          tl, (f32x4*)(out + (size_t)t0 * (NC * TP_)) + 2048 + tid);
    }
    sbar_lgkm();                            // reads done -> buffer reusable
    ori_c = ori_n; nm_c = nm_n;
  }

  // ---- rows 1..ROWS-1: compute row r, interleave stores of row r-1 --------
#pragma unroll 1
  for (int row = 1; row < ROWS; ++row) {
    const int t = t0 + row;
    if (row + 1 < ROWS) {                   // prefetch next row's gather
      ori_n = locations[pos_idx[t + 1] * TP_ + tp];
      nm_n  = norm[t + 1];
    }

    f32x4* __restrict__ o4_prev = (f32x4*)(out + (size_t)(t - 1) * (NC * TP_));
    const uint32_t base = (uint32_t)(((jl * T_ + t) * K_) * TP_ + tp);
    compute_row<true>(ori_c, nm_c, base, flip_h, mask_h, buf, bufp1, tid,
                      stg, o4_prev);

    sbar_lgkm();                            // scatter of row r visible
#pragma unroll
    for (int s = 0; s < 8; ++s)
      stg[s] = *(const f32x4*)(bufc + raddr[s]);
    if (tid < 4) {                          // tail of row r
      f32x4 tl = *(const f32x4*)(bufc + taddr);
      __builtin_nontemporal_store(
          tl, (f32x4*)(out + (size_t)t * (NC * TP_)) + 2048 + tid);
    }
    sbar_lgkm();                            // reads done -> buffer reusable
    ori_c = ori_n; nm_c = nm_n;
  }

  // ---- final burst: last row's main stores --------------------------------
  {
    f32x4* __restrict__ o4 =
        (f32x4*)(out + (size_t)(t0 + ROWS - 1) * (NC * TP_));
#pragma unroll
    for (int s = 0; s < 8; ++s)
      __builtin_nontemporal_store(stg[s], o4 + (s << 8) + tid);
  }
}

extern "C" void kernel_launch(void* const* d_in, const int* in_sizes, int n_in,
                              void* d_out, int out_size, void* d_ws, size_t ws_size,
                              hipStream_t stream) {
  const int*   locations = (const int*)d_in[0];
  const int*   pos_idx   = (const int*)d_in[1];
  const float* norm      = (const float*)d_in[2];
  float* out = (float*)d_out;

  hipLaunchKernelGGL(dist_kernel, dim3(GRID), dim3(256), 0, stream,
                     locations, pos_idx, norm, out);
}